// Round 24
// baseline (129.991 us; speedup 1.0000x reference)
//
#include <hip/hip_runtime.h>
#include <math.h>

#define B 32
#define H 16
#define LDIM 512
#define DR 64
#define DQK 192
#define DCACHE 576   // LDIM + DR
#define DV 128
#define PAGE 128
#define PAGES_PER_SEQ 32
#define MAX_KV 4096
#define NC 32
#define CHUNK 128    // MAX_KV / NC
#define NWORK (B * NC)
#define SCALE 0.07216878364870322f   // 192^-0.5

typedef float f32x4 __attribute__((ext_vector_type(4)));
typedef short bf16x8 __attribute__((ext_vector_type(8)));
typedef unsigned int u32;

__device__ __forceinline__ u32 pk2(float lo, float hi){
  u32 r;
  asm("v_cvt_pk_bf16_f32 %0, %1, %2" : "=v"(r) : "v"(lo), "v"(hi));
  return r;
}

// ---------------- K0: rope + latent row ----------------
__global__ __launch_bounds__(64) void k_prep0(
    const float* __restrict__ q, const float* __restrict__ k_c,
    const float* __restrict__ k_pe, const int* __restrict__ pos_,
    float* __restrict__ query, float* __restrict__ latent)
{
  int b = blockIdx.x;
  int lane = threadIdx.x;
  const float4* src = (const float4*)(k_c + (size_t)b * LDIM);
  float4* dst = (float4*)(latent + (size_t)b * DCACHE);
  dst[lane] = src[lane];
  dst[lane + 64] = src[lane + 64];
  int pos = pos_[b];
  if (lane < 32) {
    float invf = powf(10000.f, -(float)lane / 32.f);
    float f = (float)pos * invf;
    float c = cosf(f), s = sinf(f);
    float x1 = k_pe[b * DR + lane];
    float x2 = k_pe[b * DR + 32 + lane];
    latent[b * DCACHE + LDIM + lane] = x1 * c - x2 * s;
    latent[b * DCACHE + LDIM + 32 + lane] = x2 * c + x1 * s;
    for (int h = 0; h < H; ++h) {
      const float* qp = q + ((size_t)b * H + h) * DQK + 128;
      float y1 = qp[lane];
      float y2 = qp[32 + lane];
      query[((size_t)b * H + h) * DCACHE + LDIM + lane] = y1 * c - y2 * s;
      query[((size_t)b * H + h) * DCACHE + LDIM + 32 + lane] = y2 * c + y1 * s;
    }
  }
}

// ---------------- K1: ql_nope = q_nope @ W_UK_T ----------------
__global__ __launch_bounds__(256) void k_prep1(
    const float* __restrict__ q, const float* __restrict__ wukt,
    float* __restrict__ query)
{
  int h = blockIdx.x >> 3;
  int lt = blockIdx.x & 7;
  __shared__ float qs[B][128];
  int t = threadIdx.x;
  for (int idx = t; idx < B * 128; idx += 256) {
    int b = idx >> 7, d = idx & 127;
    qs[b][d] = q[((size_t)b * H + h) * DQK + d];
  }
  __syncthreads();
  int l = t & 63, bh = t >> 6;
  const float* wp = wukt + (size_t)h * (128 * LDIM) + lt * 64 + l;
  float acc[8];
#pragma unroll
  for (int i = 0; i < 8; ++i) acc[i] = 0.f;
  for (int d4 = 0; d4 < 32; ++d4) {
    float w0 = wp[(4 * d4 + 0) * LDIM];
    float w1 = wp[(4 * d4 + 1) * LDIM];
    float w2 = wp[(4 * d4 + 2) * LDIM];
    float w3 = wp[(4 * d4 + 3) * LDIM];
#pragma unroll
    for (int i = 0; i < 8; ++i) {
      const float4 qv = *(const float4*)&qs[bh * 8 + i][4 * d4];
      acc[i] += qv.x * w0 + qv.y * w1 + qv.z * w2 + qv.w * w3;
    }
  }
#pragma unroll
  for (int i = 0; i < 8; ++i)
    query[(((size_t)(bh * 8 + i)) * H + h) * DCACHE + lt * 64 + l] = acc[i];
}

// ---------------- K1b: pre-pack Q into bf16 MFMA fragments ----------------
__global__ __launch_bounds__(64) void k_qfrag(
    const float* __restrict__ query, unsigned short* __restrict__ qfrag)
{
  int b = blockIdx.x;
  int l = threadIdx.x;
  int g = l >> 4, hh = l & 15;
  const float* qb = query + ((size_t)(b * H + hh)) * DCACHE + g * 8;
#pragma unroll
  for (int ks = 0; ks < 18; ++ks) {
    f32x4 x = *(const f32x4*)(qb + ks * 32);
    f32x4 y = *(const f32x4*)(qb + ks * 32 + 4);
    uint4 w;
    w.x = pk2(x[0], x[1]); w.y = pk2(x[2], x[3]);
    w.z = pk2(y[0], y[1]); w.w = pk2(y[2], y[3]);
    *(uint4*)&qfrag[(((size_t)b * 18 + ks) * 64 + l) * 8] = w;
  }
}

// ---------------- K2: WAVE-AUTONOMOUS split-KV flash, bf16 MFMA --------------
// ZERO __syncthreads. Block = 2 independent waves; item = (b,c) of 128 keys,
// static assignment w = blockIdx.x (c-major). Per 16-key tile each wave loads
// K-rows directly from global as QK A-fragments; stages its 256-dim V-slice
// into a wave-PRIVATE LDS region; QK MFMA, softmax, PV over its dims.
// r22 NaN root cause fixed: the uint4-store/u16-load pair was a strict-
// aliasing (TBAA) violation -> compiler reordered LDS reads/writes with no
// barrier present. Fix: (1) V-stage writes via bf16x8 (short) = same
// effective type as reads; (2) lgkmcnt(0)+memory fence+sched_barrier between
// stage and PV reads; (3) memory fence at tile-loop top (WAR).
__global__ __launch_bounds__(128) void k_attn(
    const float* __restrict__ cache, const int* __restrict__ btab,
    const int* __restrict__ seql, const unsigned short* __restrict__ qfrag,
    const float* __restrict__ latent, float* __restrict__ mbuf,
    float* __restrict__ lbuf, float* __restrict__ ctxbuf)
{
  int t = threadIdx.x;
  int lane = t & 63, wid = t >> 6;     // wid: which 256-dim half this wave owns
  int g = lane >> 4, hh = lane & 15;

  __shared__ short vlds[2][16 * 256];  // 2 x 8KB wave-private V tiles
  short* vb = &vlds[wid][0];

  int w = blockIdx.x;
  int b = w & 31, c = w >> 5;          // c-major: adjacent blocks span batches
  int sl = seql[b];
  int start = c * CHUNK;
  int idxML = (b * NC + c) * H;
  if (start >= sl) {
    if (t < H) { mbuf[idxML + t] = -INFINITY; lbuf[idxML + t] = 0.f; }
    return;
  }
  int nvalid = min(CHUNK, sl - start);
  int ntiles = (nvalid + 15) >> 4;
  int ks_lo = 8 * wid;                 // V-stage ks range [ks_lo, ks_lo+8)

  // ---- Q fragments (bf16, pre-packed, L2-hot) ----
  bf16x8 qf[18];
  {
    const unsigned short* qfb = qfrag + ((size_t)b * 18) * 64 * 8;
#pragma unroll
    for (int ks = 0; ks < 18; ++ks)
      qf[ks] = *(const bf16x8*)&qfb[((size_t)ks * 64 + lane) * 8];
  }

  float m = -INFINITY, lsum = 0.f;
  f32x4 ctx[16];
#pragma unroll
  for (int nt = 0; nt < 16; ++nt) ctx[nt] = (f32x4)(0.f);

  for (int tb = 0; tb < ntiles; ++tb) {
    asm volatile("" ::: "memory");     // WAR fence: prior PV reads stay below
    // per-lane row pointer for key = start + tb*16 + hh (g-duplicated)
    int pos = start + tb * 16 + hh;
    int cp = min(pos, MAX_KV - 1);
    const float* rp = (pos == sl - 1)
        ? (latent + (size_t)b * DCACHE)
        : (cache + ((size_t)btab[b * PAGES_PER_SEQ + (cp >> 7)] * PAGE
                    + (cp & 127)) * DCACHE);
    const f32x4* rp4 = (const f32x4*)rp;

    // ---- QK^T from global A-fragments + private V-stage ----
    f32x4 s0 = (f32x4)(0.f);
#pragma unroll
    for (int ks = 0; ks < 18; ++ks) {
      f32x4 x = rp4[ks * 8 + g * 2];
      f32x4 y = rp4[ks * 8 + g * 2 + 1];
      union { uint4 u; bf16x8 v; } af;
      af.u.x = pk2(x[0], x[1]); af.u.y = pk2(x[2], x[3]);
      af.u.z = pk2(y[0], y[1]); af.u.w = pk2(y[2], y[3]);
      if (ks >= ks_lo && ks < ks_lo + 8) {
        int ksl = ks - ks_lo;
        u32 byte = (u32)(hh * 512 + ((ksl * 64 + g * 16) ^ ((hh & 12) << 2)));
        *(bf16x8*)((char*)vb + byte) = af.v;   // short-typed store (no TBAA)
      }
      s0 = __builtin_amdgcn_mfma_f32_16x16x32_bf16(af.v, qf[ks], s0, 0, 0, 0);
    }
    // scale + mask: lane (g,hh) holds keys {tb*16 + g*4 + r}
    int kbase = tb * 16 + g * 4;
#pragma unroll
    for (int r = 0; r < 4; ++r)
      s0[r] = (kbase + r < nvalid) ? s0[r] * SCALE : -INFINITY;
    // ---- online softmax ----
    float lm = fmaxf(fmaxf(s0[0], s0[1]), fmaxf(s0[2], s0[3]));
    lm = fmaxf(lm, __shfl_xor(lm, 16));
    lm = fmaxf(lm, __shfl_xor(lm, 32));
    float m_new = fmaxf(m, lm);
    float alpha = __expf(m - m_new);
    float p0[4], ps = 0.f;
#pragma unroll
    for (int r = 0; r < 4; ++r) {
      p0[r] = __expf(s0[r] - m_new);
      ps += p0[r];
    }
    ps += __shfl_xor(ps, 16);
    ps += __shfl_xor(ps, 32);
    lsum = lsum * alpha + ps;
    m = m_new;
    f32x4 av;
#pragma unroll
    for (int r = 0; r < 4; ++r) av[r] = __shfl(alpha, g * 4 + r);
#pragma unroll
    for (int nt = 0; nt < 16; ++nt) ctx[nt] *= av;
    // ---- P fragment: sigma slot 8g+j -> key 4g+j (j<4), else zero ----
    union { u32 wq[4]; bf16x8 v; } pu;
    pu.wq[0] = pk2(p0[0], p0[1]);
    pu.wq[1] = pk2(p0[2], p0[3]);
    pu.wq[2] = 0u;
    pu.wq[3] = 0u;
    bf16x8 pf = pu.v;
    // ---- fence: V-stage writes complete + compiler ordering before reads ----
    asm volatile("s_waitcnt lgkmcnt(0)" ::: "memory");
    __builtin_amdgcn_sched_barrier(0);
    // ---- PV over this wave's 256 dims (private LDS, swizzled) ----
#pragma unroll
    for (int nt = 0; nt < 16; ++nt) {
      bf16x8 vf;
#pragma unroll
      for (int j = 0; j < 4; ++j) {
        int key = 4 * g + j;
        u32 byte = (u32)(key * 512 + ((nt * 32 + hh * 2) ^ ((key & 12) << 2)));
        vf[j] = vb[byte >> 1];
      }
      vf[4] = 0; vf[5] = 0; vf[6] = 0; vf[7] = 0;
      ctx[nt] = __builtin_amdgcn_mfma_f32_16x16x32_bf16(pf, vf, ctx[nt], 0, 0, 0);
    }
  }

  // ---- write partials: ctx[m=head g*4+r][n=dim wid*256 + nt*16 + hh] ----
  float* cb = ctxbuf + (size_t)idxML * LDIM;
#pragma unroll
  for (int nt = 0; nt < 16; ++nt) {
    int dim = wid * 256 + nt * 16 + hh;
#pragma unroll
    for (int r = 0; r < 4; ++r) {
      int head = g * 4 + r;
      cb[(size_t)head * LDIM + dim] = ctx[nt][r];
    }
  }
  if (wid == 0 && lane < H) {
    mbuf[idxML + lane] = m;
    lbuf[idxML + lane] = lsum;
  }
}

// ---------------- K3: cross-chunk merge + ctx @ W_UV ----------------
__global__ __launch_bounds__(256) void k_out(
    const float* __restrict__ mbuf, const float* __restrict__ lbuf,
    const float* __restrict__ ctxbuf, const float* __restrict__ wuv,
    float* __restrict__ out)
{
  int h = blockIdx.x >> 3, bg = blockIdx.x & 7;
  int t = threadIdx.x, lane = t & 63, wid = t >> 6;
  __shared__ float e_lds[4][NC];
  __shared__ float invl[4];
  __shared__ float ctx[4][LDIM];
  int b = bg * 4 + wid;
  {
    float m = -INFINITY, lv = 0.f;
    if (lane < NC) {
      m = mbuf[(b * NC + lane) * H + h];
      lv = lbuf[(b * NC + lane) * H + h];
    }
    float M = m;
#pragma unroll
    for (int s = 1; s < 32; s <<= 1) M = fmaxf(M, __shfl_xor(M, s));
    float e = (lane < NC && m > -INFINITY) ? expf(m - M) : 0.f;
    float le = e * lv;
#pragma unroll
    for (int s = 1; s < 32; s <<= 1) le += __shfl_xor(le, s);
    if (lane < NC) e_lds[wid][lane] = e;
    if (lane == 0) invl[wid] = 1.f / le;
  }
  {
    float4 a0 = make_float4(0.f, 0.f, 0.f, 0.f);
    float4 a1 = make_float4(0.f, 0.f, 0.f, 0.f);
    const float* cb = ctxbuf + ((size_t)b * NC * H + h) * LDIM + lane * 8;
    for (int c = 0; c < NC; ++c) {
      float e = e_lds[wid][c];
      if (e != 0.f) {
        const float4* p = (const float4*)(cb + (size_t)c * H * LDIM);
        float4 v0 = p[0], v1 = p[1];
        a0.x += e * v0.x; a0.y += e * v0.y; a0.z += e * v0.z; a0.w += e * v0.w;
        a1.x += e * v1.x; a1.y += e * v1.y; a1.z += e * v1.z; a1.w += e * v1.w;
      }
    }
    float inv = invl[wid];
    a0.x *= inv; a0.y *= inv; a0.z *= inv; a0.w *= inv;
    a1.x *= inv; a1.y *= inv; a1.z *= inv; a1.w *= inv;
    *(float4*)&ctx[wid][lane * 8] = a0;
    *(float4*)&ctx[wid][lane * 8 + 4] = a1;
  }
  __syncthreads();
  int v = t & 127, bp = t >> 7;
  float acc0 = 0.f, acc1 = 0.f;
  const float* wp = wuv + (size_t)h * (LDIM * DV) + v;
  for (int d4 = 0; d4 < LDIM / 4; ++d4) {
    float w0 = wp[(4 * d4 + 0) * DV];
    float w1 = wp[(4 * d4 + 1) * DV];
    float w2 = wp[(4 * d4 + 2) * DV];
    float w3 = wp[(4 * d4 + 3) * DV];
    float4 c0 = *(const float4*)&ctx[bp * 2 + 0][4 * d4];
    float4 c1 = *(const float4*)&ctx[bp * 2 + 1][4 * d4];
    acc0 += c0.x * w0 + c0.y * w1 + c0.z * w2 + c0.w * w3;
    acc1 += c1.x * w0 + c1.y * w1 + c1.z * w2 + c1.w * w3;
  }
  out[(size_t)(bg * 4 + bp * 2 + 0) * (H * DV) + h * DV + v] = acc0;
  out[(size_t)(bg * 4 + bp * 2 + 1) * (H * DV) + h * DV + v] = acc1;
}

extern "C" void kernel_launch(void* const* d_in, const int* in_sizes, int n_in,
                              void* d_out, int out_size, void* d_ws, size_t ws_size,
                              hipStream_t stream) {
  const float* q     = (const float*)d_in[0];
  const float* k_c   = (const float*)d_in[1];
  const float* k_pe  = (const float*)d_in[2];
  const float* cache = (const float*)d_in[3];
  const float* wukt  = (const float*)d_in[4];
  const float* wuv   = (const float*)d_in[5];
  const int* pos     = (const int*)d_in[6];
  const int* btab    = (const int*)d_in[8];
  const int* seql    = (const int*)d_in[9];
  float* out = (float*)d_out;
  float* ws = (float*)d_ws;

  float* query  = ws;                       // B*H*576      = 294912 f
  float* latent = query + 294912;           // B*576        = 18432 f
  float* mbuf   = latent + 18432;           // B*NC*H       = 16384 f
  float* lbuf   = mbuf + 16384;             // 16384 f
  float* ctxbuf = lbuf + 16384;             // B*NC*H*512   = 8388608 f
  unsigned short* qfrag = (unsigned short*)(ctxbuf + 8388608); // B*18*64*8 u16
  // total ~35.6 MB of workspace

  hipLaunchKernelGGL(k_prep0, dim3(B), dim3(64), 0, stream, q, k_c, k_pe, pos, query, latent);
  hipLaunchKernelGGL(k_prep1, dim3(H * 8), dim3(256), 0, stream, q, wukt, query);
  hipLaunchKernelGGL(k_qfrag, dim3(B), dim3(64), 0, stream, query, qfrag);
  hipLaunchKernelGGL(k_attn, dim3(NWORK), dim3(128), 0, stream, cache, btab, seql,
                     qfrag, latent, mbuf, lbuf, ctxbuf);
  hipLaunchKernelGGL(k_out, dim3(H * 8), dim3(256), 0, stream, mbuf, lbuf, ctxbuf, wuv, out);
}

// Round 25
// 95.752 us; speedup vs baseline: 1.3576x; 1.3576x over previous
//
#include <hip/hip_runtime.h>
#include <math.h>

#define B 32
#define H 16
#define LDIM 512
#define DR 64
#define DQK 192
#define DCACHE 576   // LDIM + DR
#define DV 128
#define PAGE 128
#define PAGES_PER_SEQ 32
#define MAX_KV 4096
#define NC 32
#define CHUNK 128    // MAX_KV / NC
#define NWORK (B * NC)
#define SCALE 0.07216878364870322f   // 192^-0.5

typedef float f32x4 __attribute__((ext_vector_type(4)));
typedef short bf16x8 __attribute__((ext_vector_type(8)));
typedef unsigned int u32;

__device__ __forceinline__ u32 pk2(float lo, float hi){
  u32 r;
  asm("v_cvt_pk_bf16_f32 %0, %1, %2" : "=v"(r) : "v"(lo), "v"(hi));
  return r;
}
// LDS swizzle: permutes 16B units within 128B lines (bits 4-6 XOR).
__device__ __forceinline__ u32 swz(u32 a){
  return a ^ ((((a >> 10) ^ (a >> 7)) & 7u) << 4);
}

// ---------------- K0: rope + latent row + zero the work counter ----------------
__global__ __launch_bounds__(64) void k_prep0(
    const float* __restrict__ q, const float* __restrict__ k_c,
    const float* __restrict__ k_pe, const int* __restrict__ pos_,
    float* __restrict__ query, float* __restrict__ latent,
    int* __restrict__ counter)
{
  int b = blockIdx.x;
  int lane = threadIdx.x;
  if (b == 0 && lane == 0) counter[0] = 0;
  const float4* src = (const float4*)(k_c + (size_t)b * LDIM);
  float4* dst = (float4*)(latent + (size_t)b * DCACHE);
  dst[lane] = src[lane];
  dst[lane + 64] = src[lane + 64];
  int pos = pos_[b];
  if (lane < 32) {
    float invf = powf(10000.f, -(float)lane / 32.f);
    float f = (float)pos * invf;
    float c = cosf(f), s = sinf(f);
    float x1 = k_pe[b * DR + lane];
    float x2 = k_pe[b * DR + 32 + lane];
    latent[b * DCACHE + LDIM + lane] = x1 * c - x2 * s;
    latent[b * DCACHE + LDIM + 32 + lane] = x2 * c + x1 * s;
    for (int h = 0; h < H; ++h) {
      const float* qp = q + ((size_t)b * H + h) * DQK + 128;
      float y1 = qp[lane];
      float y2 = qp[32 + lane];
      query[((size_t)b * H + h) * DCACHE + LDIM + lane] = y1 * c - y2 * s;
      query[((size_t)b * H + h) * DCACHE + LDIM + 32 + lane] = y2 * c + y1 * s;
    }
  }
}

// ---------------- K1: ql_nope = q_nope @ W_UK_T ----------------
__global__ __launch_bounds__(256) void k_prep1(
    const float* __restrict__ q, const float* __restrict__ wukt,
    float* __restrict__ query)
{
  int h = blockIdx.x >> 3;
  int lt = blockIdx.x & 7;
  __shared__ float qs[B][128];
  int t = threadIdx.x;
  for (int idx = t; idx < B * 128; idx += 256) {
    int b = idx >> 7, d = idx & 127;
    qs[b][d] = q[((size_t)b * H + h) * DQK + d];
  }
  __syncthreads();
  int l = t & 63, bh = t >> 6;
  const float* wp = wukt + (size_t)h * (128 * LDIM) + lt * 64 + l;
  float acc[8];
#pragma unroll
  for (int i = 0; i < 8; ++i) acc[i] = 0.f;
  for (int d4 = 0; d4 < 32; ++d4) {
    float w0 = wp[(4 * d4 + 0) * LDIM];
    float w1 = wp[(4 * d4 + 1) * LDIM];
    float w2 = wp[(4 * d4 + 2) * LDIM];
    float w3 = wp[(4 * d4 + 3) * LDIM];
#pragma unroll
    for (int i = 0; i < 8; ++i) {
      const float4 qv = *(const float4*)&qs[bh * 8 + i][4 * d4];
      acc[i] += qv.x * w0 + qv.y * w1 + qv.z * w2 + qv.w * w3;
    }
  }
#pragma unroll
  for (int i = 0; i < 8; ++i)
    query[(((size_t)(bh * 8 + i)) * H + h) * DCACHE + lt * 64 + l] = acc[i];
}

// ---------------- K1b: pre-pack Q into bf16 MFMA fragments ----------------
__global__ __launch_bounds__(64) void k_qfrag(
    const float* __restrict__ query, unsigned short* __restrict__ qfrag)
{
  int b = blockIdx.x;
  int l = threadIdx.x;
  int g = l >> 4, hh = l & 15;
  const float* qb = query + ((size_t)(b * H + hh)) * DCACHE + g * 8;
#pragma unroll
  for (int ks = 0; ks < 18; ++ks) {
    f32x4 x = *(const f32x4*)(qb + ks * 32);
    f32x4 y = *(const f32x4*)(qb + ks * 32 + 4);
    uint4 w;
    w.x = pk2(x[0], x[1]); w.y = pk2(x[2], x[3]);
    w.z = pk2(y[0], y[1]); w.w = pk2(y[2], y[3]);
    *(uint4*)&qfrag[(((size_t)b * 18 + ks) * 64 + l) * 8] = w;
  }
}

// ---------------- K2: persistent split-KV flash, bf16 MFMA, 16-key tiles ------
// BEST-KNOWN config (95.97us): 768 persistent blocks (3/CU), 256 threads =
// 4 waves, stealing over 1024 (b,c) 128-key chunks (c-major, longest first).
// 16-key tiles, 18KB LDS, 2 barriers/tile, 1-tile register prefetch pinned
// after the LDS-ready barrier. Staged coalesced loads -> cvt_pk -> swizzled
// LDS; QK swapped-MFMA; sigma-trick shuffle-free P; PV per wave over 128
// dims (k-slots 4..7 zero-padded).
__global__ __launch_bounds__(256) void k_attn(
    const float* __restrict__ cache, const int* __restrict__ btab,
    const int* __restrict__ seql, const unsigned short* __restrict__ qfrag,
    const float* __restrict__ latent, float* __restrict__ mbuf,
    float* __restrict__ lbuf, float* __restrict__ ctxbuf,
    int* __restrict__ counter)
{
  int t = threadIdx.x;
  int lane = t & 63, wid = t >> 6;
  int g = lane >> 4, hh = lane & 15;
  int keyt = t >> 4, c16 = t & 15;   // staging: thread -> (key row, 16B col)

  __shared__ unsigned short kv[36 * 16 * 16];       // 18 KB
  __shared__ unsigned long long rowp[CHUNK];        // 1 KB
  __shared__ int witem;

  // fixed per-thread swizzled LDS write offsets (one 8B unit each)
  u32 wroff[9];
#pragma unroll
  for (int i = 0; i < 9; ++i) {
    int col = c16 + 16 * i;            // 16B-unit column within the row
    int dg = col >> 2;
    int doff8 = (col & 3) * 8;         // byte offset within key row
    wroff[i] = swz((u32)(dg * 512 + keyt * 32 + doff8));
  }

  for (;;) {
    if (t == 0) witem = atomicAdd(counter, 1);
    __syncthreads();
    int w = witem;
    __syncthreads();
    if (w >= NWORK) break;
    int b = w & 31, c = w >> 5;        // c-major queue order
    int sl = seql[b];
    int start = c * CHUNK;
    int idxML = (b * NC + c) * H;
    if (start >= sl) {
      if (t < H) { mbuf[idxML + t] = -INFINITY; lbuf[idxML + t] = 0.f; }
      continue;
    }
    int nvalid = min(CHUNK, sl - start);
    int ntiles = (nvalid + 15) >> 4;

    if (t < CHUNK) {
      int pos = start + t;
      int cp = min(pos, MAX_KV - 1);
      const float* rp = (pos == sl - 1)
          ? (latent + (size_t)b * DCACHE)
          : (cache + ((size_t)btab[b * PAGES_PER_SEQ + (cp >> 7)] * PAGE
                      + (cp & 127)) * DCACHE);
      rowp[t] = (unsigned long long)(uintptr_t)rp;
    }

    // ---- Q fragments (bf16, pre-packed, coalesced, L2-hot) ----
    bf16x8 qf[18];
    {
      const unsigned short* qfb = qfrag + ((size_t)b * 18) * 64 * 8;
#pragma unroll
      for (int ks = 0; ks < 18; ++ks)
        qf[ks] = *(const bf16x8*)&qfb[((size_t)ks * 64 + lane) * 8];
    }
    __syncthreads();   // rowp ready

    // staging registers: 9 x 16B units/thread (one key-row slice each)
    f32x4 ra[9];
    auto issue_loads = [&](int tb) {
      const char* rb = (const char*)(uintptr_t)rowp[tb * 16 + keyt]
                       + (size_t)(c16 * 16);
#pragma unroll
      for (int i = 0; i < 9; ++i)
        ra[i] = *(const f32x4*)(rb + i * 256);
    };
    issue_loads(0);

    float m = -INFINITY, lsum = 0.f;
    f32x4 ctx[8];
#pragma unroll
    for (int nt = 0; nt < 8; ++nt) ctx[nt] = (f32x4)(0.f);

    for (int tb = 0; tb < ntiles; ++tb) {
      __syncthreads();   // prev compute done
      // ---- stage 16-key tile to LDS (bf16, subtiled+swizzled, b64 writes) ----
#pragma unroll
      for (int i = 0; i < 9; ++i) {
        uint2 wq;
        wq.x = pk2(ra[i][0], ra[i][1]);
        wq.y = pk2(ra[i][2], ra[i][3]);
        *(uint2*)((char*)kv + wroff[i]) = wq;
      }
      __syncthreads();   // LDS ready
      if (tb + 1 < ntiles) {
        issue_loads(tb + 1);
        __builtin_amdgcn_sched_barrier(0);
      }

      // ---- QK^T (swapped): D[m=key][n=head], one 16-key m-tile ----
      __builtin_amdgcn_s_setprio(1);
      f32x4 s0 = (f32x4)(0.f);
#pragma unroll
      for (int ks = 0; ks < 18; ++ks) {
        int dg = 2 * ks + (g >> 1);
        u32 bbytes = (u32)(dg * 512 + hh * 32 + (g & 1) * 16);
        union { uint4 u; bf16x8 v; } a0;
        a0.u = *(const uint4*)((const char*)kv + swz(bbytes));
        s0 = __builtin_amdgcn_mfma_f32_16x16x32_bf16(a0.v, qf[ks], s0, 0, 0, 0);
      }
      __builtin_amdgcn_s_setprio(0);
      int kbase = tb * 16 + g * 4;
#pragma unroll
      for (int r = 0; r < 4; ++r)
        s0[r] = (kbase + r < nvalid) ? s0[r] * SCALE : -INFINITY;
      // ---- online softmax ----
      float lm = fmaxf(fmaxf(s0[0], s0[1]), fmaxf(s0[2], s0[3]));
      lm = fmaxf(lm, __shfl_xor(lm, 16));
      lm = fmaxf(lm, __shfl_xor(lm, 32));
      float m_new = fmaxf(m, lm);
      float alpha = __expf(m - m_new);
      float p0[4], ps = 0.f;
#pragma unroll
      for (int r = 0; r < 4; ++r) {
        p0[r] = __expf(s0[r] - m_new);
        ps += p0[r];
      }
      ps += __shfl_xor(ps, 16);
      ps += __shfl_xor(ps, 32);
      lsum = lsum * alpha + ps;
      m = m_new;
      f32x4 av;
#pragma unroll
      for (int r = 0; r < 4; ++r) av[r] = __shfl(alpha, g * 4 + r);
#pragma unroll
      for (int nt = 0; nt < 8; ++nt) ctx[nt] *= av;
      // ---- P fragment: sigma slot 8g+j -> key 4g+j (j<4), else zero ----
      union { u32 w[4]; bf16x8 v; } pu;
      pu.w[0] = pk2(p0[0], p0[1]);
      pu.w[1] = pk2(p0[2], p0[3]);
      pu.w[2] = 0u;
      pu.w[3] = 0u;
      bf16x8 pf = pu.v;
      // ---- PV: per wave 8 n-tiles of 16 dims; vf j<4 = V[key 4g+j][dim] ----
      __builtin_amdgcn_s_setprio(1);
#pragma unroll
      for (int nt = 0; nt < 8; ++nt) {
        int dgv = wid * 8 + nt;
        bf16x8 vf;
#pragma unroll
        for (int j = 0; j < 4; ++j) {
          u32 byte = (u32)(dgv * 512 + (4 * g + j) * 32 + hh * 2);
          vf[j] = (short)kv[swz(byte) >> 1];
        }
        vf[4] = 0; vf[5] = 0; vf[6] = 0; vf[7] = 0;
        ctx[nt] = __builtin_amdgcn_mfma_f32_16x16x32_bf16(pf, vf, ctx[nt], 0, 0, 0);
      }
      __builtin_amdgcn_s_setprio(0);
    }

    // ---- write partials: ctx[m=head g*4+r][n=dim wid*128+nt*16+hh] ----
    float* cb = ctxbuf + (size_t)idxML * LDIM;
#pragma unroll
    for (int nt = 0; nt < 8; ++nt) {
      int dim = wid * 128 + nt * 16 + hh;
#pragma unroll
      for (int r = 0; r < 4; ++r) {
        int head = g * 4 + r;
        cb[(size_t)head * LDIM + dim] = ctx[nt][r];
      }
    }
    if (wid == 0 && lane < H) {
      mbuf[idxML + lane] = m;
      lbuf[idxML + lane] = lsum;
    }
  }
}

// ---------------- K3: cross-chunk merge + ctx @ W_UV ----------------
__global__ __launch_bounds__(256) void k_out(
    const float* __restrict__ mbuf, const float* __restrict__ lbuf,
    const float* __restrict__ ctxbuf, const float* __restrict__ wuv,
    float* __restrict__ out)
{
  int h = blockIdx.x >> 3, bg = blockIdx.x & 7;
  int t = threadIdx.x, lane = t & 63, wid = t >> 6;
  __shared__ float e_lds[4][NC];
  __shared__ float invl[4];
  __shared__ float ctx[4][LDIM];
  int b = bg * 4 + wid;
  {
    float m = -INFINITY, lv = 0.f;
    if (lane < NC) {
      m = mbuf[(b * NC + lane) * H + h];
      lv = lbuf[(b * NC + lane) * H + h];
    }
    float M = m;
#pragma unroll
    for (int s = 1; s < 32; s <<= 1) M = fmaxf(M, __shfl_xor(M, s));
    float e = (lane < NC && m > -INFINITY) ? expf(m - M) : 0.f;
    float le = e * lv;
#pragma unroll
    for (int s = 1; s < 32; s <<= 1) le += __shfl_xor(le, s);
    if (lane < NC) e_lds[wid][lane] = e;
    if (lane == 0) invl[wid] = 1.f / le;
  }
  {
    float4 a0 = make_float4(0.f, 0.f, 0.f, 0.f);
    float4 a1 = make_float4(0.f, 0.f, 0.f, 0.f);
    const float* cb = ctxbuf + ((size_t)b * NC * H + h) * LDIM + lane * 8;
    for (int c = 0; c < NC; ++c) {
      float e = e_lds[wid][c];
      if (e != 0.f) {
        const float4* p = (const float4*)(cb + (size_t)c * H * LDIM);
        float4 v0 = p[0], v1 = p[1];
        a0.x += e * v0.x; a0.y += e * v0.y; a0.z += e * v0.z; a0.w += e * v0.w;
        a1.x += e * v1.x; a1.y += e * v1.y; a1.z += e * v1.z; a1.w += e * v1.w;
      }
    }
    float inv = invl[wid];
    a0.x *= inv; a0.y *= inv; a0.z *= inv; a0.w *= inv;
    a1.x *= inv; a1.y *= inv; a1.z *= inv; a1.w *= inv;
    *(float4*)&ctx[wid][lane * 8] = a0;
    *(float4*)&ctx[wid][lane * 8 + 4] = a1;
  }
  __syncthreads();
  int v = t & 127, bp = t >> 7;
  float acc0 = 0.f, acc1 = 0.f;
  const float* wp = wuv + (size_t)h * (LDIM * DV) + v;
  for (int d4 = 0; d4 < LDIM / 4; ++d4) {
    float w0 = wp[(4 * d4 + 0) * DV];
    float w1 = wp[(4 * d4 + 1) * DV];
    float w2 = wp[(4 * d4 + 2) * DV];
    float w3 = wp[(4 * d4 + 3) * DV];
    float4 c0 = *(const float4*)&ctx[bp * 2 + 0][4 * d4];
    float4 c1 = *(const float4*)&ctx[bp * 2 + 1][4 * d4];
    acc0 += c0.x * w0 + c0.y * w1 + c0.z * w2 + c0.w * w3;
    acc1 += c1.x * w0 + c1.y * w1 + c1.z * w2 + c1.w * w3;
  }
  out[(size_t)(bg * 4 + bp * 2 + 0) * (H * DV) + h * DV + v] = acc0;
  out[(size_t)(bg * 4 + bp * 2 + 1) * (H * DV) + h * DV + v] = acc1;
}

extern "C" void kernel_launch(void* const* d_in, const int* in_sizes, int n_in,
                              void* d_out, int out_size, void* d_ws, size_t ws_size,
                              hipStream_t stream) {
  const float* q     = (const float*)d_in[0];
  const float* k_c   = (const float*)d_in[1];
  const float* k_pe  = (const float*)d_in[2];
  const float* cache = (const float*)d_in[3];
  const float* wukt  = (const float*)d_in[4];
  const float* wuv   = (const float*)d_in[5];
  const int* pos     = (const int*)d_in[6];
  const int* btab    = (const int*)d_in[8];
  const int* seql    = (const int*)d_in[9];
  float* out = (float*)d_out;
  float* ws = (float*)d_ws;

  float* query  = ws;                       // B*H*576      = 294912 f
  float* latent = query + 294912;           // B*576        = 18432 f
  float* mbuf   = latent + 18432;           // B*NC*H       = 16384 f
  float* lbuf   = mbuf + 16384;             // 16384 f
  float* ctxbuf = lbuf + 16384;             // B*NC*H*512   = 8388608 f
  unsigned short* qfrag = (unsigned short*)(ctxbuf + 8388608); // B*18*64*8 u16
  int* counter  = (int*)(qfrag + 294912);   // 1 int
  // total ~35.6 MB of workspace

  hipLaunchKernelGGL(k_prep0, dim3(B), dim3(64), 0, stream, q, k_c, k_pe, pos, query, latent, counter);
  hipLaunchKernelGGL(k_prep1, dim3(H * 8), dim3(256), 0, stream, q, wukt, query);
  hipLaunchKernelGGL(k_qfrag, dim3(B), dim3(64), 0, stream, query, qfrag);
  hipLaunchKernelGGL(k_attn, dim3(768), dim3(256), 0, stream, cache, btab, seql,
                     qfrag, latent, mbuf, lbuf, ctxbuf, counter);
  hipLaunchKernelGGL(k_out, dim3(H * 8), dim3(256), 0, stream, mbuf, lbuf, ctxbuf, wuv, out);
}